// Round 12
// baseline (203.450 us; speedup 1.0000x reference)
//
#include <hip/hip_runtime.h>

// R26 (resubmit — R11 slot was "container failed twice"; source re-audited:
// sink write max 2MB << 256MB ws, template/launch syntax valid, no new
// builtins; R2->R3 precedent for verbatim resubmit after flake).
// MEASUREMENT ROUND 2 — phase ablation. R25 established k_all=33.5us warm,
// ~2x my phase model, and k_all is INVISIBLE in rocprof top-5 (fills 43us).
//   Variant B (MODE=1): setup + P1 + P2, then sink pfl[0..783] -> d_ws
//   (keeps hsu->P2->pfl chain live; d_ws unchecked). Launch [B,B,B,full].
//   dB = (T - 116.06 - ~1.5)/3.  Decision: dB<15 -> attack fc1 (latency-
//   serialized w_fc1 loads @64-VGPR cap); 15-25 -> attack P2 (A-read
//   conflicts/fence/chain); >25 -> measure A=setup+P1 next.
//   Bonus: if k_all<1> shows in top-5, read VGPR_Count (spill check, R15).
// Kernel body = R24 verbatim (passed, absmax 0.0156); MODE templating only.
// Pinned: (R14) no cross-block sync; (R18) occupancy alone null; (R19)
// pixel-major hsu, k=tap*8+ch; (R20) fill ~43us unconditional; (R21/24)
// barrier elimination ~null; (R22/23) split-K MFMA needs per-K B-frags;
// (R25) budget: fill 43 + k_all 33.5 + harness ~37 => floor ~80, k_all is
// the only lever; rocprof can't see k_all -> ablate by duration.

#define HS 58    // hsu row stride in pixels (16B each)
#define FS 72    // fsu row stride in f16 (144B; 36 u32 ≡ 4 mod 32)
#define FSW 36   // fsu row stride in u32

typedef _Float16 half2_t __attribute__((ext_vector_type(2)));
typedef _Float16 f16x8 __attribute__((ext_vector_type(8)));
typedef float f32x4 __attribute__((ext_vector_type(4)));
typedef float f32x2 __attribute__((ext_vector_type(2)));
typedef float f32x4u __attribute__((ext_vector_type(4), aligned(4)));

__device__ __forceinline__ unsigned pack_f16(float a, float b) {
  union { half2_t h; unsigned u; } z;
  z.h[0] = (_Float16)a;  // RNE
  z.h[1] = (_Float16)b;
  return z.u;
}

__device__ __forceinline__ f16x8 as_f16x8(uint4 u) {
  union { uint4 u; f16x8 f; } z;
  z.u = u;
  return z.f;
}

template <int MODE>  // 0 = full; 1 = stop after P2, sink pfl -> ws
__global__ __launch_bounds__(1024, 8) void k_all(
    const float* __restrict__ x, const float* __restrict__ w1,
    const float* __restrict__ b1, const float* __restrict__ w2,
    const float* __restrict__ b2, const float* __restrict__ wp,
    const float* __restrict__ bp, const float* __restrict__ w_fc1,
    const float* __restrict__ b_fc1, const float* __restrict__ w_fc2,
    const float* __restrict__ b_fc2, float* __restrict__ out,
    float* __restrict__ ws) {
  // hsu: [hr 0..57][hc 0..57][ch 0..7] f16; hr = pooled_row+1 (ring = zero)
  __shared__ __align__(16) unsigned hsu[HS * HS * 4];  // 53.8 KB
  __shared__ __align__(16) unsigned bwl[768];          // 3.0 KB [oc16][tap12][w4]
  __shared__ __align__(16) unsigned fsu[122 * FSW];    // 17.6 KB f16 K-major rows
  __shared__ __align__(16) float pfl[784];             // 3.1 KB
  __shared__ float h1s[64];
  const int tid = threadIdx.x;
  const int b = blockIdx.x;
  const int l = tid & 63;
  const int wv = __builtin_amdgcn_readfirstlane(tid >> 6);  // wave id 0..15
  const float* xb = x + (long)b * 12544;

  // ---- setup (same barrier region as P1: disjoint LDS writes) ----
  if (tid < 228) {  // zero the padding ring (P1 writes interior only)
    int i = tid, hr, hc;
    if (i < 58) { hr = 0; hc = i; }
    else if (i < 116) { hr = 57; hc = i - 58; }
    else if (i < 172) { hr = i - 115; hc = 0; }
    else { hr = i - 171; hc = 57; }
    *(uint4*)(hsu + (hr * HS + hc) * 4) = make_uint4(0u, 0u, 0u, 0u);
  }
  // Pack conv2 weights: bwl[(oc*12 + tap)*4 + w] = f16pair(ch 2w, 2w+1).
  // Taps 9..11 are dead K-slots (zero B) so A may read any valid address.
  if (tid < 768) {
    int t = tid, oc = t / 48, rem = t - oc * 48;
    int tap = rem >> 2, w = rem & 3;
    unsigned v = 0u;
    if (tap < 9)
      v = pack_f16(w2[(oc * 8 + 2 * w) * 9 + tap],
                   w2[(oc * 8 + 2 * w + 1) * 9 + tap]);
    bwl[t] = v;
  }

  // ---- P1: conv1(1->8)+bias+relu+maxpool2 -> f16 pixel-major LDS tile ----
  for (int task = tid; task < 3136; task += 1024) {
    int gr = task / 56, gc = task - gr * 56;  // pooled coords 0..55
    float win[4][4];
    int iy0 = 2 * gr - 1, ix0 = 2 * gc - 1;
    if (gr >= 1 && gr <= 54 && gc >= 1 && gc <= 54) {
      const float* xp = xb + iy0 * 112 + ix0;  // interior: all in-bounds
#pragma unroll
      for (int rr = 0; rr < 4; ++rr) {
        f32x4u v = *(const f32x4u*)(xp + rr * 112);  // unaligned dwordx4
        win[rr][0] = v.x; win[rr][1] = v.y; win[rr][2] = v.z; win[rr][3] = v.w;
      }
    } else {
#pragma unroll
      for (int rr = 0; rr < 4; ++rr) {
        int iy = iy0 + rr;
        bool yok = (unsigned)iy < 112u;
#pragma unroll
        for (int qq = 0; qq < 4; ++qq) {
          int ix = ix0 + qq;
          win[rr][qq] = (yok && (unsigned)ix < 112u) ? xb[iy * 112 + ix] : 0.f;
        }
      }
    }
    float hv[8];
#pragma unroll
    for (int ch = 0; ch < 8; ++ch) {
      f32x2 sA = {0.f, 0.f};
      f32x2 sB = {0.f, 0.f};
#pragma unroll
      for (int ty = 0; ty < 3; ++ty)
#pragma unroll
        for (int tx = 0; tx < 3; ++tx) {
          float wk = w1[ch * 9 + ty * 3 + tx];
          f32x2 wkk = {wk, wk};
          f32x2 xa = {win[ty][tx], win[ty][tx + 1]};
          f32x2 xb2 = {win[ty + 1][tx], win[ty + 1][tx + 1]};
          sA = __builtin_elementwise_fma(xa, wkk, sA);
          sB = __builtin_elementwise_fma(xb2, wkk, sB);
        }
      f32x2 sm = __builtin_elementwise_max(sA, sB);
      float m = fmaxf(sm.x, sm.y);
      hv[ch] = fmaxf(m + b1[ch], 0.f);
    }
    uint4 hw;
    hw.x = pack_f16(hv[0], hv[1]);
    hw.y = pack_f16(hv[2], hv[3]);
    hw.z = pack_f16(hv[4], hv[5]);
    hw.w = pack_f16(hv[6], hv[7]);
    *(uint4*)(hsu + ((gr + 1) * HS + gc + 1) * 4) = hw;  // one b128 store
  }
  __syncthreads();  // BARRIER 1 (only barrier before fc1!)

  // ---- P2: conv2+pool+relu via MFMA; wave-local, ZERO barriers ----
  {
    const int q = l >> 4;       // k-quarter / f-pixel role (a=q>>1, b=q&1)
    const int oc = l & 15;      // also: patch-row-in-window for projection
    const int yoff = 2 * ((l >> 3) & 1) + ((l >> 1) & 1);  // 2a+dy
    const int xoff = 2 * ((l >> 2) & 1) + (l & 1);         // 2b+dx
    int poff[3];
#pragma unroll
    for (int kk = 0; kk < 3; ++kk) {
      int t = kk * 4 + q;
      int tt = t < 9 ? t : 8;  // dead taps alias tap 8 (B there is zero)
      int ty = tt / 3, tx = tt - ty * 3;
      poff[kk] = ((yoff + ty) * HS + xoff + tx) * 4;  // u32 units
    }
    uint4 bu0 = *(const uint4*)(bwl + (oc * 12 + 0 + q) * 4);
    uint4 bu1 = *(const uint4*)(bwl + (oc * 12 + 4 + q) * 4);
    uint4 bu2 = *(const uint4*)(bwl + (oc * 12 + 8 + q) * 4);
    const float b2v = b2[oc];

    // Projection B-frags: MFMA#1 needs B[k=q*8+j][col=oc] = wp[oc][q*8+j];
    // MFMA#2 (k 32..63 of the K=64 contraction) needs wp[oc][32+q*8+j].
    f16x8 wpf0 = {}, wpf1 = {};
    float bpj = 0.f;
    if (oc < 4) {
      const float* wr = wp + oc * 64 + q * 8;
      float4 wa = *(const float4*)(wr);
      float4 wb = *(const float4*)(wr + 4);
      float4 wc = *(const float4*)(wr + 32);
      float4 wd = *(const float4*)(wr + 36);
      union { unsigned u[4]; f16x8 v; } u0, u1;
      u0.u[0] = pack_f16(wa.x, wa.y);
      u0.u[1] = pack_f16(wa.z, wa.w);
      u0.u[2] = pack_f16(wb.x, wb.y);
      u0.u[3] = pack_f16(wb.z, wb.w);
      u1.u[0] = pack_f16(wc.x, wc.y);
      u1.u[1] = pack_f16(wc.z, wc.w);
      u1.u[2] = pack_f16(wd.x, wd.y);
      u1.u[3] = pack_f16(wd.z, wd.w);
      wpf0 = u0.v;
      wpf1 = u1.v;
      bpj = bp[oc];
    }

    _Float16* fsh = (_Float16*)fsu;
    const int NP = (wv < 4) ? 13 : 12;              // patches owned (contig)
    const int G0 = (wv < 4) ? 13 * wv : 12 * wv + 4;
    const int RW = 7 * wv;                          // private fsu row base
    const int npA = (NP + 1) >> 1;

    for (int hlf = 0; hlf < 2; ++hlf) {
      const int np = hlf ? NP - npA : npA;          // 7|6 then 6
      const int g0 = hlf ? G0 + npA : G0;
      for (int i = 0; i < np; ++i) {
        int p = g0 + i;
        int py = p / 14, px = p - py * 14;
        int pb = (4 * py * HS + 4 * px) * 4;  // u32 offset of patch origin
        uint4 a0u = *(const uint4*)(hsu + pb + poff[0]);
        uint4 a1u = *(const uint4*)(hsu + pb + poff[1]);
        uint4 a2u = *(const uint4*)(hsu + pb + poff[2]);
        f32x4 acc = {0.f, 0.f, 0.f, 0.f};
        acc = __builtin_amdgcn_mfma_f32_16x16x32_f16(as_f16x8(a0u), as_f16x8(bu0), acc, 0, 0, 0);
        acc = __builtin_amdgcn_mfma_f32_16x16x32_f16(as_f16x8(a1u), as_f16x8(bu1), acc, 0, 0, 0);
        acc = __builtin_amdgcn_mfma_f32_16x16x32_f16(as_f16x8(a2u), as_f16x8(bu2), acc, 0, 0, 0);
        float mx = fmaxf(fmaxf(acc[0], acc[1]), fmaxf(acc[2], acc[3]));
        float fv = fmaxf(mx + b2v, 0.f);  // f[oc][f-pixel q] of patch p
        // K-major row: k = oc*4 + q (patch feature index)
        fsh[(RW + i) * FS + oc * 4 + q] = (_Float16)fv;
      }
      // FENCE: writes above via _Float16*, reads below via unsigned* (TBAA
      // no-alias). Order them; HW same-wave DS ops are in-order.
      asm volatile("s_waitcnt lgkmcnt(0)" ::: "memory");
      __builtin_amdgcn_sched_barrier(0);
      // Wave-local projection: pf[p][ot] = sum_k f[p][k]*wp[ot][k], K=64.
      // A rows RW..RW+15 (rows >= np are neighbor garbage -> unstored).
      const unsigned* ar = fsu + (RW + oc) * FSW + q * 4;
      uint4 pa0 = *(const uint4*)(ar);        // k 0..31 slice
      uint4 pa1 = *(const uint4*)(ar + 16);   // k 32..63 slice
      f32x4 pc = {0.f, 0.f, 0.f, 0.f};
      pc = __builtin_amdgcn_mfma_f32_16x16x32_f16(as_f16x8(pa0), wpf0, pc, 0, 0, 0);
      pc = __builtin_amdgcn_mfma_f32_16x16x32_f16(as_f16x8(pa1), wpf1, pc, 0, 0, 0);
      if (oc < 4) {
#pragma unroll
        for (int i2 = 0; i2 < 4; ++i2) {
          int prow = q * 4 + i2;  // C row = patch within window
          if (prow < np) pfl[(g0 + prow) * 4 + oc] = pc[i2] + bpj;
        }
      }
      // Keep next half's writes below this half's reads (WAR on rows 0..5).
      asm volatile("" ::: "memory");
    }
  }
  __syncthreads();  // BARRIER 2

  if (MODE == 1) {
    // Sink: consume ALL of pfl (tid 0..783 covers every element) -> d_ws.
    // Keeps setup+P1+P2 fully live; skips fc1/fc2. Uniform return, no
    // barrier below in this instantiation.
    int pi = tid;
    if (pi >= 784) pi -= 784;
    ws[((long)b << 10) + tid] = pfl[pi];
    return;
  }

  // ---- fc1: thread (j = tid>>4, q16 = tid&15); 16-way K-split ----
  {
    int j = tid >> 4, q16 = tid & 15;
    const float* wrow = w_fc1 + j * 784;
    float acc = 0.f;
    for (int lp = q16; lp < 196; lp += 16) {
      float4 w4 = *(const float4*)(wrow + lp * 4);
      float4 p4 = *(const float4*)(pfl + lp * 4);
      acc += w4.x * p4.x + w4.y * p4.y + w4.z * p4.z + w4.w * p4.w;
    }
    acc += __shfl_down(acc, 8, 16);
    acc += __shfl_down(acc, 4, 16);
    acc += __shfl_down(acc, 2, 16);
    acc += __shfl_down(acc, 1, 16);
    if (q16 == 0) h1s[j] = fmaxf(acc + b_fc1[j], 0.f);
  }
  __syncthreads();  // BARRIER 3

  // ---- fc2 + log_softmax: wave 0 only (shuffle-reduce, no LDS temps) ----
  if (wv == 0) {
    float h = h1s[l];
    float lg[10];
#pragma unroll
    for (int o = 0; o < 10; ++o) {
      float t = h * w_fc2[o * 64 + l];
#pragma unroll
      for (int off = 32; off; off >>= 1) t += __shfl_xor(t, off);
      lg[o] = t + b_fc2[o];  // every lane holds all 10 logits
    }
    float mx = lg[0];
#pragma unroll
    for (int o = 1; o < 10; ++o) mx = fmaxf(mx, lg[o]);
    float se = 0.f;
#pragma unroll
    for (int o = 0; o < 10; ++o) se += __expf(lg[o] - mx);
    float ls = mx + __logf(se);
#pragma unroll
    for (int o = 0; o < 10; ++o)  // static-index stores (no scratch)
      if (l == o) out[b * 10 + o] = lg[o] - ls;
  }
}

extern "C" void kernel_launch(void* const* d_in, const int* in_sizes, int n_in,
                              void* d_out, int out_size, void* d_ws, size_t ws_size,
                              hipStream_t stream) {
  const float* x = (const float*)d_in[0];
  const float* w1 = (const float*)d_in[1];
  const float* b1 = (const float*)d_in[2];
  const float* w2 = (const float*)d_in[3];
  const float* b2 = (const float*)d_in[4];
  const float* wp = (const float*)d_in[5];
  const float* bp = (const float*)d_in[6];
  const float* wf1 = (const float*)d_in[7];
  const float* bf1 = (const float*)d_in[8];
  const float* wf2 = (const float*)d_in[9];
  const float* bf2 = (const float*)d_in[10];
  float* ws = (float*)d_ws;  // 256 MB workspace; 2 MB used as ablation sink

  // MEASUREMENT: dB = (total - 116.06)/3, B = setup+P1+P2 (fc skipped).
  k_all<1><<<dim3(512), 1024, 0, stream>>>(x, w1, b1, w2, b2, wp, bp, wf1,
                                           bf1, wf2, bf2, (float*)d_out, ws);
  k_all<1><<<dim3(512), 1024, 0, stream>>>(x, w1, b1, w2, b2, wp, bp, wf1,
                                           bf1, wf2, bf2, (float*)d_out, ws);
  k_all<1><<<dim3(512), 1024, 0, stream>>>(x, w1, b1, w2, b2, wp, bp, wf1,
                                           bf1, wf2, bf2, (float*)d_out, ws);
  k_all<0><<<dim3(512), 1024, 0, stream>>>(x, w1, b1, w2, b2, wp, bp, wf1,
                                           bf1, wf2, bf2, (float*)d_out, ws);
}

// Round 13
// 187.296 us; speedup vs baseline: 1.0863x; 1.0863x over previous
//
#include <hip/hip_runtime.h>

// R27: MEASUREMENT ROUND 3 (final) — isolate P1. R26 gave front(setup+P1+P2)
// = 29.1us, fc = 4.4us of k_all = 33.5us warm. Front is 2x its issue model
// (~15us) -> locate the stall before attacking.
//   Variant A (MODE=2): setup + P1 + barrier, then XOR-reduce ALL of hsu ->
//   ws (keeps hsu live, ~0.3us cost). Launch [A,A,A,full].
//   dA = (T-116.06)/3 - 0.3 => P1; P2 = 29.1 - dA.
//   Decision: dA<10 -> attack P2 (single-fence 13-patch loop + unroll);
//   10-16 -> attack both (P1 pipeline + P2 unroll); >16 -> attack P1
//   (software-pipelined loads, f32x4u codegen check, wave balance).
// Kernel body = R24 verbatim (passed, absmax 0.0156); MODE templating only.
// Pinned: (R14) no cross-block sync; (R18) occupancy alone null; (R19)
// pixel-major hsu, k=tap*8+ch; (R20) fill ~43us unconditional; (R21/24)
// barrier elimination ~null; (R22/23) split-K MFMA needs per-K B-frags;
// (R25) k_all=33.5, floor ~80-83; (R26) front=29.1, fc=4.4 — fc is NOT
// the target; rocprof can't see k_all -> ablate by duration.

#define HS 58    // hsu row stride in pixels (16B each)
#define FS 72    // fsu row stride in f16 (144B; 36 u32 ≡ 4 mod 32)
#define FSW 36   // fsu row stride in u32

typedef _Float16 half2_t __attribute__((ext_vector_type(2)));
typedef _Float16 f16x8 __attribute__((ext_vector_type(8)));
typedef float f32x4 __attribute__((ext_vector_type(4)));
typedef float f32x2 __attribute__((ext_vector_type(2)));
typedef float f32x4u __attribute__((ext_vector_type(4), aligned(4)));

__device__ __forceinline__ unsigned pack_f16(float a, float b) {
  union { half2_t h; unsigned u; } z;
  z.h[0] = (_Float16)a;  // RNE
  z.h[1] = (_Float16)b;
  return z.u;
}

__device__ __forceinline__ f16x8 as_f16x8(uint4 u) {
  union { uint4 u; f16x8 f; } z;
  z.u = u;
  return z.f;
}

template <int MODE>  // 0 = full; 2 = stop after P1, XOR-sink hsu -> ws
__global__ __launch_bounds__(1024, 8) void k_all(
    const float* __restrict__ x, const float* __restrict__ w1,
    const float* __restrict__ b1, const float* __restrict__ w2,
    const float* __restrict__ b2, const float* __restrict__ wp,
    const float* __restrict__ bp, const float* __restrict__ w_fc1,
    const float* __restrict__ b_fc1, const float* __restrict__ w_fc2,
    const float* __restrict__ b_fc2, float* __restrict__ out,
    float* __restrict__ ws) {
  // hsu: [hr 0..57][hc 0..57][ch 0..7] f16; hr = pooled_row+1 (ring = zero)
  __shared__ __align__(16) unsigned hsu[HS * HS * 4];  // 53.8 KB
  __shared__ __align__(16) unsigned bwl[768];          // 3.0 KB [oc16][tap12][w4]
  __shared__ __align__(16) unsigned fsu[122 * FSW];    // 17.6 KB f16 K-major rows
  __shared__ __align__(16) float pfl[784];             // 3.1 KB
  __shared__ float h1s[64];
  const int tid = threadIdx.x;
  const int b = blockIdx.x;
  const int l = tid & 63;
  const int wv = __builtin_amdgcn_readfirstlane(tid >> 6);  // wave id 0..15
  const float* xb = x + (long)b * 12544;

  // ---- setup (same barrier region as P1: disjoint LDS writes) ----
  if (tid < 228) {  // zero the padding ring (P1 writes interior only)
    int i = tid, hr, hc;
    if (i < 58) { hr = 0; hc = i; }
    else if (i < 116) { hr = 57; hc = i - 58; }
    else if (i < 172) { hr = i - 115; hc = 0; }
    else { hr = i - 171; hc = 57; }
    *(uint4*)(hsu + (hr * HS + hc) * 4) = make_uint4(0u, 0u, 0u, 0u);
  }
  // Pack conv2 weights: bwl[(oc*12 + tap)*4 + w] = f16pair(ch 2w, 2w+1).
  // Taps 9..11 are dead K-slots (zero B) so A may read any valid address.
  if (tid < 768) {
    int t = tid, oc = t / 48, rem = t - oc * 48;
    int tap = rem >> 2, w = rem & 3;
    unsigned v = 0u;
    if (tap < 9)
      v = pack_f16(w2[(oc * 8 + 2 * w) * 9 + tap],
                   w2[(oc * 8 + 2 * w + 1) * 9 + tap]);
    bwl[t] = v;
  }

  // ---- P1: conv1(1->8)+bias+relu+maxpool2 -> f16 pixel-major LDS tile ----
  for (int task = tid; task < 3136; task += 1024) {
    int gr = task / 56, gc = task - gr * 56;  // pooled coords 0..55
    float win[4][4];
    int iy0 = 2 * gr - 1, ix0 = 2 * gc - 1;
    if (gr >= 1 && gr <= 54 && gc >= 1 && gc <= 54) {
      const float* xp = xb + iy0 * 112 + ix0;  // interior: all in-bounds
#pragma unroll
      for (int rr = 0; rr < 4; ++rr) {
        f32x4u v = *(const f32x4u*)(xp + rr * 112);  // unaligned dwordx4
        win[rr][0] = v.x; win[rr][1] = v.y; win[rr][2] = v.z; win[rr][3] = v.w;
      }
    } else {
#pragma unroll
      for (int rr = 0; rr < 4; ++rr) {
        int iy = iy0 + rr;
        bool yok = (unsigned)iy < 112u;
#pragma unroll
        for (int qq = 0; qq < 4; ++qq) {
          int ix = ix0 + qq;
          win[rr][qq] = (yok && (unsigned)ix < 112u) ? xb[iy * 112 + ix] : 0.f;
        }
      }
    }
    float hv[8];
#pragma unroll
    for (int ch = 0; ch < 8; ++ch) {
      f32x2 sA = {0.f, 0.f};
      f32x2 sB = {0.f, 0.f};
#pragma unroll
      for (int ty = 0; ty < 3; ++ty)
#pragma unroll
        for (int tx = 0; tx < 3; ++tx) {
          float wk = w1[ch * 9 + ty * 3 + tx];
          f32x2 wkk = {wk, wk};
          f32x2 xa = {win[ty][tx], win[ty][tx + 1]};
          f32x2 xb2 = {win[ty + 1][tx], win[ty + 1][tx + 1]};
          sA = __builtin_elementwise_fma(xa, wkk, sA);
          sB = __builtin_elementwise_fma(xb2, wkk, sB);
        }
      f32x2 sm = __builtin_elementwise_max(sA, sB);
      float m = fmaxf(sm.x, sm.y);
      hv[ch] = fmaxf(m + b1[ch], 0.f);
    }
    uint4 hw;
    hw.x = pack_f16(hv[0], hv[1]);
    hw.y = pack_f16(hv[2], hv[3]);
    hw.z = pack_f16(hv[4], hv[5]);
    hw.w = pack_f16(hv[6], hv[7]);
    *(uint4*)(hsu + ((gr + 1) * HS + gc + 1) * 4) = hw;  // one b128 store
  }
  __syncthreads();  // BARRIER 1 (only barrier before fc1!)

  if (MODE == 2) {
    // Sink: XOR-reduce ALL of hsu (keeps setup+P1 fully live), one 4B store
    // per thread (2 MB total grid writes, ~0.3us cost — discounted in dA).
    unsigned acc = 0u;
    for (int i = tid; i < HS * HS * 4; i += 1024) acc ^= hsu[i];
    ws[((long)b << 10) + tid] = __uint_as_float(acc);
    return;
  }

  // ---- P2: conv2+pool+relu via MFMA; wave-local, ZERO barriers ----
  {
    const int q = l >> 4;       // k-quarter / f-pixel role (a=q>>1, b=q&1)
    const int oc = l & 15;      // also: patch-row-in-window for projection
    const int yoff = 2 * ((l >> 3) & 1) + ((l >> 1) & 1);  // 2a+dy
    const int xoff = 2 * ((l >> 2) & 1) + (l & 1);         // 2b+dx
    int poff[3];
#pragma unroll
    for (int kk = 0; kk < 3; ++kk) {
      int t = kk * 4 + q;
      int tt = t < 9 ? t : 8;  // dead taps alias tap 8 (B there is zero)
      int ty = tt / 3, tx = tt - ty * 3;
      poff[kk] = ((yoff + ty) * HS + xoff + tx) * 4;  // u32 units
    }
    uint4 bu0 = *(const uint4*)(bwl + (oc * 12 + 0 + q) * 4);
    uint4 bu1 = *(const uint4*)(bwl + (oc * 12 + 4 + q) * 4);
    uint4 bu2 = *(const uint4*)(bwl + (oc * 12 + 8 + q) * 4);
    const float b2v = b2[oc];

    // Projection B-frags: MFMA#1 needs B[k=q*8+j][col=oc] = wp[oc][q*8+j];
    // MFMA#2 (k 32..63 of the K=64 contraction) needs wp[oc][32+q*8+j].
    f16x8 wpf0 = {}, wpf1 = {};
    float bpj = 0.f;
    if (oc < 4) {
      const float* wr = wp + oc * 64 + q * 8;
      float4 wa = *(const float4*)(wr);
      float4 wb = *(const float4*)(wr + 4);
      float4 wc = *(const float4*)(wr + 32);
      float4 wd = *(const float4*)(wr + 36);
      union { unsigned u[4]; f16x8 v; } u0, u1;
      u0.u[0] = pack_f16(wa.x, wa.y);
      u0.u[1] = pack_f16(wa.z, wa.w);
      u0.u[2] = pack_f16(wb.x, wb.y);
      u0.u[3] = pack_f16(wb.z, wb.w);
      u1.u[0] = pack_f16(wc.x, wc.y);
      u1.u[1] = pack_f16(wc.z, wc.w);
      u1.u[2] = pack_f16(wd.x, wd.y);
      u1.u[3] = pack_f16(wd.z, wd.w);
      wpf0 = u0.v;
      wpf1 = u1.v;
      bpj = bp[oc];
    }

    _Float16* fsh = (_Float16*)fsu;
    const int NP = (wv < 4) ? 13 : 12;              // patches owned (contig)
    const int G0 = (wv < 4) ? 13 * wv : 12 * wv + 4;
    const int RW = 7 * wv;                          // private fsu row base
    const int npA = (NP + 1) >> 1;

    for (int hlf = 0; hlf < 2; ++hlf) {
      const int np = hlf ? NP - npA : npA;          // 7|6 then 6
      const int g0 = hlf ? G0 + npA : G0;
      for (int i = 0; i < np; ++i) {
        int p = g0 + i;
        int py = p / 14, px = p - py * 14;
        int pb = (4 * py * HS + 4 * px) * 4;  // u32 offset of patch origin
        uint4 a0u = *(const uint4*)(hsu + pb + poff[0]);
        uint4 a1u = *(const uint4*)(hsu + pb + poff[1]);
        uint4 a2u = *(const uint4*)(hsu + pb + poff[2]);
        f32x4 acc = {0.f, 0.f, 0.f, 0.f};
        acc = __builtin_amdgcn_mfma_f32_16x16x32_f16(as_f16x8(a0u), as_f16x8(bu0), acc, 0, 0, 0);
        acc = __builtin_amdgcn_mfma_f32_16x16x32_f16(as_f16x8(a1u), as_f16x8(bu1), acc, 0, 0, 0);
        acc = __builtin_amdgcn_mfma_f32_16x16x32_f16(as_f16x8(a2u), as_f16x8(bu2), acc, 0, 0, 0);
        float mx = fmaxf(fmaxf(acc[0], acc[1]), fmaxf(acc[2], acc[3]));
        float fv = fmaxf(mx + b2v, 0.f);  // f[oc][f-pixel q] of patch p
        // K-major row: k = oc*4 + q (patch feature index)
        fsh[(RW + i) * FS + oc * 4 + q] = (_Float16)fv;
      }
      // FENCE: writes above via _Float16*, reads below via unsigned* (TBAA
      // no-alias). Order them; HW same-wave DS ops are in-order.
      asm volatile("s_waitcnt lgkmcnt(0)" ::: "memory");
      __builtin_amdgcn_sched_barrier(0);
      // Wave-local projection: pf[p][ot] = sum_k f[p][k]*wp[ot][k], K=64.
      // A rows RW..RW+15 (rows >= np are neighbor garbage -> unstored).
      const unsigned* ar = fsu + (RW + oc) * FSW + q * 4;
      uint4 pa0 = *(const uint4*)(ar);        // k 0..31 slice
      uint4 pa1 = *(const uint4*)(ar + 16);   // k 32..63 slice
      f32x4 pc = {0.f, 0.f, 0.f, 0.f};
      pc = __builtin_amdgcn_mfma_f32_16x16x32_f16(as_f16x8(pa0), wpf0, pc, 0, 0, 0);
      pc = __builtin_amdgcn_mfma_f32_16x16x32_f16(as_f16x8(pa1), wpf1, pc, 0, 0, 0);
      if (oc < 4) {
#pragma unroll
        for (int i2 = 0; i2 < 4; ++i2) {
          int prow = q * 4 + i2;  // C row = patch within window
          if (prow < np) pfl[(g0 + prow) * 4 + oc] = pc[i2] + bpj;
        }
      }
      // Keep next half's writes below this half's reads (WAR on rows 0..5).
      asm volatile("" ::: "memory");
    }
  }
  __syncthreads();  // BARRIER 2

  // ---- fc1: thread (j = tid>>4, q16 = tid&15); 16-way K-split ----
  {
    int j = tid >> 4, q16 = tid & 15;
    const float* wrow = w_fc1 + j * 784;
    float acc = 0.f;
    for (int lp = q16; lp < 196; lp += 16) {
      float4 w4 = *(const float4*)(wrow + lp * 4);
      float4 p4 = *(const float4*)(pfl + lp * 4);
      acc += w4.x * p4.x + w4.y * p4.y + w4.z * p4.z + w4.w * p4.w;
    }
    acc += __shfl_down(acc, 8, 16);
    acc += __shfl_down(acc, 4, 16);
    acc += __shfl_down(acc, 2, 16);
    acc += __shfl_down(acc, 1, 16);
    if (q16 == 0) h1s[j] = fmaxf(acc + b_fc1[j], 0.f);
  }
  __syncthreads();  // BARRIER 3

  // ---- fc2 + log_softmax: wave 0 only (shuffle-reduce, no LDS temps) ----
  if (wv == 0) {
    float h = h1s[l];
    float lg[10];
#pragma unroll
    for (int o = 0; o < 10; ++o) {
      float t = h * w_fc2[o * 64 + l];
#pragma unroll
      for (int off = 32; off; off >>= 1) t += __shfl_xor(t, off);
      lg[o] = t + b_fc2[o];  // every lane holds all 10 logits
    }
    float mx = lg[0];
#pragma unroll
    for (int o = 1; o < 10; ++o) mx = fmaxf(mx, lg[o]);
    float se = 0.f;
#pragma unroll
    for (int o = 0; o < 10; ++o) se += __expf(lg[o] - mx);
    float ls = mx + __logf(se);
#pragma unroll
    for (int o = 0; o < 10; ++o)  // static-index stores (no scratch)
      if (l == o) out[b * 10 + o] = lg[o] - ls;
  }
}

extern "C" void kernel_launch(void* const* d_in, const int* in_sizes, int n_in,
                              void* d_out, int out_size, void* d_ws, size_t ws_size,
                              hipStream_t stream) {
  const float* x = (const float*)d_in[0];
  const float* w1 = (const float*)d_in[1];
  const float* b1 = (const float*)d_in[2];
  const float* w2 = (const float*)d_in[3];
  const float* b2 = (const float*)d_in[4];
  const float* wp = (const float*)d_in[5];
  const float* bp = (const float*)d_in[6];
  const float* wf1 = (const float*)d_in[7];
  const float* bf1 = (const float*)d_in[8];
  const float* wf2 = (const float*)d_in[9];
  const float* bf2 = (const float*)d_in[10];
  float* ws = (float*)d_ws;  // 256 MB workspace; 2 MB used as ablation sink

  // MEASUREMENT: dA = (total - 116.06)/3 - 0.3, A = setup+P1 only.
  k_all<2><<<dim3(512), 1024, 0, stream>>>(x, w1, b1, w2, b2, wp, bp, wf1,
                                           bf1, wf2, bf2, (float*)d_out, ws);
  k_all<2><<<dim3(512), 1024, 0, stream>>>(x, w1, b1, w2, b2, wp, bp, wf1,
                                           bf1, wf2, bf2, (float*)d_out, ws);
  k_all<2><<<dim3(512), 1024, 0, stream>>>(x, w1, b1, w2, b2, wp, bp, wf1,
                                           bf1, wf2, bf2, (float*)d_out, ws);
  k_all<0><<<dim3(512), 1024, 0, stream>>>(x, w1, b1, w2, b2, wp, bp, wf1,
                                           bf1, wf2, bf2, (float*)d_out, ws);
}

// Round 15
// 111.036 us; speedup vs baseline: 1.8323x; 1.6868x over previous
//
#include <hip/hip_runtime.h>

// R29 = R28 + the missing barrier: P1 now READS setup-produced LDS (wpl),
// so setup and P1 can no longer share a barrier region (R28 raced: conv8
// read wpl before tids 768..791 wrote it -> absmax 2.92). One added
// __syncthreads() after setup (~0.1us, R21 measured barriers ~null).
// R28 P1 surgery kept verbatim (P2/fc = R24 verbatim, verified):
//   1) conv1 via fdot2: row-dot = fdot2(f16 pair taps01) + f32 fma(tap2);
//      weight pairs in LDS wpl[24] (broadcast reads); x pairs via pkrtz.
//   2) border/interior split: interior 54x54 dense (pure fast path/wave),
//      220 ring pixels on tids 804..1023.
// Pinned: (R14) no cross-block sync; (R15) VGPR<=64; (R18) occupancy null;
// (R19) pixel-major hsu, k=tap*8+ch; (R20) fill ~43us unconditional;
// (R21/24) barrier count ~null; (R22/23) per-K-step MFMA B-frags;
// (R25-27) k_all=33.5 = P1 23.4 + P2 5.7 + fc 4.4, harness floor ~83;
// (R28) setup/P1 region-sharing is only legal if P1 reads none of setup's
// LDS products — NEW INVARIANT, violated once, cost a round.
// Predict: absmax 0.02-0.035; P1 23.4->~15; total 116 -> ~107-110.
// If <3us: P1 is latency-structural -> stage x via LDS or declare ceiling.

#define HS 58    // hsu row stride in pixels (16B each)
#define FS 72    // fsu row stride in f16 (144B; 36 u32 ≡ 4 mod 32)
#define FSW 36   // fsu row stride in u32

typedef _Float16 half2_t __attribute__((ext_vector_type(2)));
typedef __fp16 fp16r2 __attribute__((ext_vector_type(2)));  // cvt_pkrtz ret
typedef _Float16 f16x8 __attribute__((ext_vector_type(8)));
typedef float f32x4 __attribute__((ext_vector_type(4)));
typedef float f32x4u __attribute__((ext_vector_type(4), aligned(4)));

__device__ __forceinline__ unsigned pack_f16(float a, float b) {
  union { half2_t h; unsigned u; } z;
  z.h[0] = (_Float16)a;  // RNE
  z.h[1] = (_Float16)b;
  return z.u;
}

__device__ __forceinline__ half2_t pkrtz2(float a, float b) {
#if __has_builtin(__builtin_amdgcn_cvt_pkrtz)
  union { fp16r2 r; half2_t h; } z;
  z.r = __builtin_amdgcn_cvt_pkrtz(a, b);
  return z.h;
#else
  half2_t h;
  h[0] = (_Float16)a;
  h[1] = (_Float16)b;
  return h;
#endif
}

__device__ __forceinline__ half2_t as_h2(unsigned u) {
  union { unsigned u; half2_t h; } z;
  z.u = u;
  return z.h;
}

__device__ __forceinline__ f16x8 as_f16x8(uint4 u) {
  union { uint4 u; f16x8 f; } z;
  z.u = u;
  return z.f;
}

__device__ __forceinline__ float fdot2_(half2_t a, half2_t b, float c) {
#if __has_builtin(__builtin_amdgcn_fdot2)
  return __builtin_amdgcn_fdot2(a, b, c, false);
#else
  return c + (float)a[0] * (float)b[0] + (float)a[1] * (float)b[1];
#endif
}

// conv1 8ch on a 4x4 f32 window via fdot2 (taps01 f16) + fma (tap2 f32),
// then 2x2 maxpool + bias + relu. wpl = LDS weight-pair table [ch*3+t].
__device__ __forceinline__ void conv8(const float win[4][4],
                                      const unsigned* wpl,
                                      const float* __restrict__ w1,
                                      const float* __restrict__ b1,
                                      float hv[8]) {
  half2_t p0[4], p1[4];
#pragma unroll
  for (int r = 0; r < 4; ++r) {
    p0[r] = pkrtz2(win[r][0], win[r][1]);
    p1[r] = pkrtz2(win[r][1], win[r][2]);
  }
#pragma unroll
  for (int ch = 0; ch < 8; ++ch) {
    float s00 = 0.f, s01 = 0.f, s10 = 0.f, s11 = 0.f;
#pragma unroll
    for (int t = 0; t < 3; ++t) {
      half2_t w01 = as_h2(wpl[ch * 3 + t]);
      float w2 = w1[ch * 9 + t * 3 + 2];  // uniform -> SGPR
      s00 = fdot2_(p0[t], w01, s00);
      s00 = __builtin_fmaf(w2, win[t][2], s00);
      s01 = fdot2_(p1[t], w01, s01);
      s01 = __builtin_fmaf(w2, win[t][3], s01);
      s10 = fdot2_(p0[t + 1], w01, s10);
      s10 = __builtin_fmaf(w2, win[t + 1][2], s10);
      s11 = fdot2_(p1[t + 1], w01, s11);
      s11 = __builtin_fmaf(w2, win[t + 1][3], s11);
    }
    float m = fmaxf(fmaxf(s00, s01), fmaxf(s10, s11));
    hv[ch] = fmaxf(m + b1[ch], 0.f);
  }
}

__global__ __launch_bounds__(1024, 8) void k_all(
    const float* __restrict__ x, const float* __restrict__ w1,
    const float* __restrict__ b1, const float* __restrict__ w2,
    const float* __restrict__ b2, const float* __restrict__ wp,
    const float* __restrict__ bp, const float* __restrict__ w_fc1,
    const float* __restrict__ b_fc1, const float* __restrict__ w_fc2,
    const float* __restrict__ b_fc2, float* __restrict__ out) {
  // hsu: [hr 0..57][hc 0..57][ch 0..7] f16; hr = pooled_row+1 (ring = zero)
  __shared__ __align__(16) unsigned hsu[HS * HS * 4];  // 53.8 KB
  __shared__ __align__(16) unsigned bwl[768];          // 3.0 KB [oc16][tap12][w4]
  __shared__ __align__(16) unsigned wpl[24];           // conv1 w-pairs [ch*3+t]
  __shared__ __align__(16) unsigned fsu[122 * FSW];    // 17.6 KB f16 K-major
  __shared__ __align__(16) float pfl[784];             // 3.1 KB
  __shared__ float h1s[64];
  const int tid = threadIdx.x;
  const int b = blockIdx.x;
  const int l = tid & 63;
  const int wv = __builtin_amdgcn_readfirstlane(tid >> 6);  // wave id 0..15
  const float* xb = x + (long)b * 12544;

  // ---- setup ----
  if (tid < 228) {  // zero the padding ring (P1 writes interior only)
    int i = tid, hr, hc;
    if (i < 58) { hr = 0; hc = i; }
    else if (i < 116) { hr = 57; hc = i - 58; }
    else if (i < 172) { hr = i - 115; hc = 0; }
    else { hr = i - 171; hc = 57; }
    *(uint4*)(hsu + (hr * HS + hc) * 4) = make_uint4(0u, 0u, 0u, 0u);
  }
  // Pack conv2 weights: bwl[(oc*12 + tap)*4 + w] = f16pair(ch 2w, 2w+1).
  if (tid < 768) {
    int t = tid, oc = t / 48, rem = t - oc * 48;
    int tap = rem >> 2, w = rem & 3;
    unsigned v = 0u;
    if (tap < 9)
      v = pack_f16(w2[(oc * 8 + 2 * w) * 9 + tap],
                   w2[(oc * 8 + 2 * w + 1) * 9 + tap]);
    bwl[t] = v;
  }
  // Pack conv1 weight pairs (taps 0,1 per row) for the fdot2 path. RNE.
  if (tid >= 768 && tid < 792) {
    int t2 = tid - 768;  // ch*3 + t
    int ch = t2 / 3, t = t2 - ch * 3;
    wpl[t2] = pack_f16(w1[ch * 9 + t * 3], w1[ch * 9 + t * 3 + 1]);
  }
  __syncthreads();  // BARRIER 0 — P1 reads wpl (R28 raced without this)

  // ---- P1: conv1+bias+relu+maxpool2 -> f16 pixel-major LDS tile ----
  // Interior (54x54): dense enumeration -> every wave is pure fast path.
  for (int t = tid; t < 2916; t += 1024) {
    int gr = 1 + t / 54, gc = 1 + t % 54;  // pooled coords, interior only
    const float* xp = xb + (2 * gr - 1) * 112 + (2 * gc - 1);
    float win[4][4];
#pragma unroll
    for (int rr = 0; rr < 4; ++rr) {
      f32x4u v = *(const f32x4u*)(xp + rr * 112);
      win[rr][0] = v.x; win[rr][1] = v.y; win[rr][2] = v.z; win[rr][3] = v.w;
    }
    float hv[8];
    conv8(win, wpl, w1, b1, hv);
    uint4 hw;
    hw.x = pack_f16(hv[0], hv[1]);
    hw.y = pack_f16(hv[2], hv[3]);
    hw.z = pack_f16(hv[4], hv[5]);
    hw.w = pack_f16(hv[6], hv[7]);
    *(uint4*)(hsu + ((gr + 1) * HS + gc + 1) * 4) = hw;
  }
  // Border ring (220 pixels): tids 804..1023, guarded window build.
  if (tid >= 804) {
    int i = tid - 804;  // 0..219
    int gr, gc;
    if (i < 56) { gr = 0; gc = i; }
    else if (i < 112) { gr = 55; gc = i - 56; }
    else if (i < 166) { gr = i - 111; gc = 0; }   // rows 1..54, left
    else { gr = i - 165; gc = 55; }               // rows 1..54, right
    int iy0 = 2 * gr - 1, ix0 = 2 * gc - 1;
    float win[4][4];
#pragma unroll
    for (int rr = 0; rr < 4; ++rr) {
      int iy = iy0 + rr;
      bool yok = (unsigned)iy < 112u;
#pragma unroll
      for (int qq = 0; qq < 4; ++qq) {
        int ix = ix0 + qq;
        win[rr][qq] = (yok && (unsigned)ix < 112u) ? xb[iy * 112 + ix] : 0.f;
      }
    }
    float hv[8];
    conv8(win, wpl, w1, b1, hv);
    uint4 hw;
    hw.x = pack_f16(hv[0], hv[1]);
    hw.y = pack_f16(hv[2], hv[3]);
    hw.z = pack_f16(hv[4], hv[5]);
    hw.w = pack_f16(hv[6], hv[7]);
    *(uint4*)(hsu + ((gr + 1) * HS + gc + 1) * 4) = hw;
  }
  __syncthreads();  // BARRIER 1

  // ---- P2: conv2+pool+relu via MFMA; wave-local (R24 verbatim) ----
  {
    const int q = l >> 4;       // k-quarter / f-pixel role (a=q>>1, b=q&1)
    const int oc = l & 15;      // also: patch-row-in-window for projection
    const int yoff = 2 * ((l >> 3) & 1) + ((l >> 1) & 1);  // 2a+dy
    const int xoff = 2 * ((l >> 2) & 1) + (l & 1);         // 2b+dx
    int poff[3];
#pragma unroll
    for (int kk = 0; kk < 3; ++kk) {
      int t = kk * 4 + q;
      int tt = t < 9 ? t : 8;  // dead taps alias tap 8 (B there is zero)
      int ty = tt / 3, tx = tt - ty * 3;
      poff[kk] = ((yoff + ty) * HS + xoff + tx) * 4;  // u32 units
    }
    uint4 bu0 = *(const uint4*)(bwl + (oc * 12 + 0 + q) * 4);
    uint4 bu1 = *(const uint4*)(bwl + (oc * 12 + 4 + q) * 4);
    uint4 bu2 = *(const uint4*)(bwl + (oc * 12 + 8 + q) * 4);
    const float b2v = b2[oc];

    // Projection B-frags: MFMA#1 wp[oc][q*8+j]; MFMA#2 wp[oc][32+q*8+j].
    f16x8 wpf0 = {}, wpf1 = {};
    float bpj = 0.f;
    if (oc < 4) {
      const float* wr = wp + oc * 64 + q * 8;
      float4 wa = *(const float4*)(wr);
      float4 wb = *(const float4*)(wr + 4);
      float4 wc = *(const float4*)(wr + 32);
      float4 wd = *(const float4*)(wr + 36);
      union { unsigned u[4]; f16x8 v; } u0, u1;
      u0.u[0] = pack_f16(wa.x, wa.y);
      u0.u[1] = pack_f16(wa.z, wa.w);
      u0.u[2] = pack_f16(wb.x, wb.y);
      u0.u[3] = pack_f16(wb.z, wb.w);
      u1.u[0] = pack_f16(wc.x, wc.y);
      u1.u[1] = pack_f16(wc.z, wc.w);
      u1.u[2] = pack_f16(wd.x, wd.y);
      u1.u[3] = pack_f16(wd.z, wd.w);
      wpf0 = u0.v;
      wpf1 = u1.v;
      bpj = bp[oc];
    }

    _Float16* fsh = (_Float16*)fsu;
    const int NP = (wv < 4) ? 13 : 12;              // patches owned (contig)
    const int G0 = (wv < 4) ? 13 * wv : 12 * wv + 4;
    const int RW = 7 * wv;                          // private fsu row base
    const int npA = (NP + 1) >> 1;

    for (int hlf = 0; hlf < 2; ++hlf) {
      const int np = hlf ? NP - npA : npA;          // 7|6 then 6
      const int g0 = hlf ? G0 + npA : G0;
      for (int i = 0; i < np; ++i) {
        int p = g0 + i;
        int py = p / 14, px = p - py * 14;
        int pb = (4 * py * HS + 4 * px) * 4;  // u32 offset of patch origin
        uint4 a0u = *(const uint4*)(hsu + pb + poff[0]);
        uint4 a1u = *(const uint4*)(hsu + pb + poff[1]);
        uint4 a2u = *(const uint4*)(hsu + pb + poff[2]);
        f32x4 acc = {0.f, 0.f, 0.f, 0.f};
        acc = __builtin_amdgcn_mfma_f32_16x16x32_f16(as_f16x8(a0u), as_f16x8(bu0), acc, 0, 0, 0);
        acc = __builtin_amdgcn_mfma_f32_16x16x32_f16(as_f16x8(a1u), as_f16x8(bu1), acc, 0, 0, 0);
        acc = __builtin_amdgcn_mfma_f32_16x16x32_f16(as_f16x8(a2u), as_f16x8(bu2), acc, 0, 0, 0);
        float mx = fmaxf(fmaxf(acc[0], acc[1]), fmaxf(acc[2], acc[3]));
        float fv = fmaxf(mx + b2v, 0.f);  // f[oc][f-pixel q] of patch p
        fsh[(RW + i) * FS + oc * 4 + q] = (_Float16)fv;
      }
      // FENCE: writes via _Float16*, reads via unsigned* (TBAA no-alias).
      asm volatile("s_waitcnt lgkmcnt(0)" ::: "memory");
      __builtin_amdgcn_sched_barrier(0);
      const unsigned* ar = fsu + (RW + oc) * FSW + q * 4;
      uint4 pa0 = *(const uint4*)(ar);        // k 0..31 slice
      uint4 pa1 = *(const uint4*)(ar + 16);   // k 32..63 slice
      f32x4 pc = {0.f, 0.f, 0.f, 0.f};
      pc = __builtin_amdgcn_mfma_f32_16x16x32_f16(as_f16x8(pa0), wpf0, pc, 0, 0, 0);
      pc = __builtin_amdgcn_mfma_f32_16x16x32_f16(as_f16x8(pa1), wpf1, pc, 0, 0, 0);
      if (oc < 4) {
#pragma unroll
        for (int i2 = 0; i2 < 4; ++i2) {
          int prow = q * 4 + i2;  // C row = patch within window
          if (prow < np) pfl[(g0 + prow) * 4 + oc] = pc[i2] + bpj;
        }
      }
      asm volatile("" ::: "memory");  // WAR: next half's writes stay below
    }
  }
  __syncthreads();  // BARRIER 2

  // ---- fc1: thread (j = tid>>4, q16 = tid&15); 16-way K-split ----
  {
    int j = tid >> 4, q16 = tid & 15;
    const float* wrow = w_fc1 + j * 784;
    float acc = 0.f;
    for (int lp = q16; lp < 196; lp += 16) {
      float4 w4 = *(const float4*)(wrow + lp * 4);
      float4 p4 = *(const float4*)(pfl + lp * 4);
      acc += w4.x * p4.x + w4.y * p4.y + w4.z * p4.z + w4.w * p4.w;
    }
    acc += __shfl_down(acc, 8, 16);
    acc += __shfl_down(acc, 4, 16);
    acc += __shfl_down(acc, 2, 16);
    acc += __shfl_down(acc, 1, 16);
    if (q16 == 0) h1s[j] = fmaxf(acc + b_fc1[j], 0.f);
  }
  __syncthreads();  // BARRIER 3

  // ---- fc2 + log_softmax: wave 0 only ----
  if (wv == 0) {
    float h = h1s[l];
    float lg[10];
#pragma unroll
    for (int o = 0; o < 10; ++o) {
      float t = h * w_fc2[o * 64 + l];
#pragma unroll
      for (int off = 32; off; off >>= 1) t += __shfl_xor(t, off);
      lg[o] = t + b_fc2[o];  // every lane holds all 10 logits
    }
    float mx = lg[0];
#pragma unroll
    for (int o = 1; o < 10; ++o) mx = fmaxf(mx, lg[o]);
    float se = 0.f;
#pragma unroll
    for (int o = 0; o < 10; ++o) se += __expf(lg[o] - mx);
    float ls = mx + __logf(se);
#pragma unroll
    for (int o = 0; o < 10; ++o)  // static-index stores (no scratch)
      if (l == o) out[b * 10 + o] = lg[o] - ls;
  }
}

extern "C" void kernel_launch(void* const* d_in, const int* in_sizes, int n_in,
                              void* d_out, int out_size, void* d_ws, size_t ws_size,
                              hipStream_t stream) {
  const float* x = (const float*)d_in[0];
  const float* w1 = (const float*)d_in[1];
  const float* b1 = (const float*)d_in[2];
  const float* w2 = (const float*)d_in[3];
  const float* b2 = (const float*)d_in[4];
  const float* wp = (const float*)d_in[5];
  const float* bp = (const float*)d_in[6];
  const float* wf1 = (const float*)d_in[7];
  const float* bf1 = (const float*)d_in[8];
  const float* wf2 = (const float*)d_in[9];
  const float* bf2 = (const float*)d_in[10];
  (void)d_ws; (void)ws_size;  // workspace unused

  k_all<<<dim3(512), 1024, 0, stream>>>(x, w1, b1, w2, b2, wp, bp, wf1, bf1,
                                        wf2, bf2, (float*)d_out);
}